// Round 9
// baseline (197.433 us; speedup 1.0000x reference)
//
#include <hip/hip_runtime.h>
#include <hip/hip_bf16.h>
#include <type_traits>

typedef unsigned short u16;
typedef __attribute__((ext_vector_type(8))) short bf16x8;
typedef __attribute__((ext_vector_type(4))) float f32x4;
typedef __attribute__((ext_vector_type(2))) unsigned int u32x2;

#define B_  4
#define T_  2048
#define C_  1024
#define H_  16
#define DH_ 64
#define M_  (B_*T_)   // 8192

// async global->LDS, 16B per lane; LDS dest = wave-uniform base + lane*16
#define GLDS16(g, l) __builtin_amdgcn_global_load_lds( \
    (const __attribute__((address_space(1))) void*)(g), \
    (__attribute__((address_space(3))) void*)(l), 16, 0, 0)

__device__ __forceinline__ u16 f2b(float f) {
  union { __hip_bfloat16 h; u16 u; } cv;
  cv.h = __float2bfloat16(f);
  return cv.u;
}

// pack two f32 -> [bf16(a) | bf16(b)<<16] in 3 VALU ops: round-half-up via +0x8000,
// then one v_perm_b32 picks the two high halves. (perm sel: bytes 0-3 <- src1,
// 4-7 <- src0; 0x07060302 = [ua.b2, ua.b3, ub.b2, ub.b3].)
__device__ __forceinline__ unsigned pkbf16(float a, float b) {
  unsigned ua = __builtin_bit_cast(unsigned, a) + 0x8000u;
  unsigned ub = __builtin_bit_cast(unsigned, b) + 0x8000u;
  return __builtin_amdgcn_perm(ub, ua, 0x07060302u);
}

// ---------------- all fp32 -> bf16 casts in one launch ----------------
// W_q is pre-scaled by sqrt(log2(e)/8): both Q and K flow through W_q (reference bug),
// so QK^T arrives pre-multiplied by log2(e)/sqrt(64) and attn's softmax is a bare exp2.
__global__ void cast_all_kernel(const float* __restrict__ x,  const float* __restrict__ w0,
                                const float* __restrict__ w1, const float* __restrict__ w2,
                                u16* __restrict__ xo, u16* __restrict__ o0,
                                u16* __restrict__ o1, u16* __restrict__ o2) {
  int bid = blockIdx.x;
  const float* src; u16* dst; int blk;
  float sc = 1.0f;
  if (bid < 8192) { src = x; dst = xo; blk = bid; }
  else {
    int k = bid - 8192, w = k >> 10;
    src = (w == 0) ? w0 : (w == 1) ? w1 : w2;
    dst = (w == 0) ? o0 : (w == 1) ? o1 : o2;
    blk = k & 1023;
    if (w == 0) sc = 0.42466088f;     // sqrt(log2(e)/8)
  }
  int i = (blk * 256 + threadIdx.x) * 4;
  float4 v = *(const float4*)(src + i);
  unsigned lo = (unsigned)f2b(v.x * sc) | ((unsigned)f2b(v.y * sc) << 16);
  unsigned hi = (unsigned)f2b(v.z * sc) | ((unsigned)f2b(v.w * sc) << 16);
  uint2 p; p.x = lo; p.y = hi;
  *(uint2*)(dst + i) = p;
}

// ---------------- pipelined GEMM: 128x128 tile, 4 waves, counted vmcnt, 2 blk/CU ----
// C[m,n] = sum_k A[m,k]*B[n,k], BK=64, K=1024 (16 k-tiles).
// A: 3 bufs (48KB), B: 2 bufs (32KB) -> 80KB LDS, EXACTLY 2 blocks/CU (160KB):
// co-resident blocks cover each other's vmcnt/barrier stalls. Counted-vmcnt ledger
// (4-load stages): prologue B0,A0,A1 = 12 in flight; per tile t issue B(t+1),A(t+2)
// then vmcnt(12); tails vmcnt(8), vmcnt(0).
// MODE 0: bf16 scatter epilogue (Q half -> [B,H,T,Dh], V half -> Vt [B,H,Dh,T]).
// MODE 1: fp32 linear out [M,N].
template<int MODE>
__global__ __launch_bounds__(256, 2) void gemm128_kernel(
    const u16* __restrict__ A, const u16* __restrict__ Bm, void* __restrict__ Cout)
{
  constexpr int K = 1024;
  constexpr int NT = K / 64;                 // 16 k-tiles
  __shared__ __align__(16) u16 As[3][128 * 64];   // 48KB
  __shared__ __align__(16) u16 Bs[2][128 * 64];   // 32KB

  const int tid  = threadIdx.x;
  const int wave = tid >> 6, lane = tid & 63;     // wave 0..3
  const int quad = lane >> 4, l15 = lane & 15;
  const int x7   = l15 & 7;
  const int wr = wave >> 1, wc = wave & 1;        // 2x2 wave grid, 64x64 tiles
  // XCD-chunked swizzle (bijective: gridDim.x==64 -> 8 x-panels per XCD).
  const int ord = blockIdx.y * gridDim.x + blockIdx.x;  // dispatch order (x fastest)
  const int xcd = ord & 7;
  const int loc = ord >> 3;
  const int xl  = loc & 7;
  const int yy  = loc >> 3;
  const int tm = (xcd * 8 + xl) * 128, tn = yy * 128;

  f32x4 acc[4][4] = {};

  auto stageA = [&](int t, int bi) {
    const int k0 = t * 64;
#pragma unroll
    for (int it = 0; it < 4; it++) {
      int ch  = it * 256 + tid;       // 0..1023 chunks (128 rows x 8)
      int row = ch >> 3;
      int cc  = (ch & 7) ^ (row & 7);
      GLDS16(A + (size_t)(tm + row) * K + k0 + cc * 8, &As[bi][(it * 256 + wave * 64) * 8]);
    }
  };
  auto stageB = [&](int t, int bi) {
    const int k0 = t * 64;
#pragma unroll
    for (int it = 0; it < 4; it++) {
      int ch  = it * 256 + tid;
      int row = ch >> 3;
      int cc  = (ch & 7) ^ (row & 7);
      GLDS16(Bm + (size_t)(tn + row) * K + k0 + cc * 8, &Bs[bi][(it * 256 + wave * 64) * 8]);
    }
  };

  // prologue: B(0) [4], A(0) [4], A(1) [4]  -> 12 vmem insts in flight per wave
  stageB(0, 0);
  stageA(0, 0);
  stageA(1, 1);

  int bufA = 0, bufAn = 2;     // t%3 and (t+2)%3 trackers
  for (int t = 0; t < NT; t++) {
    // barrier_A: every wave is done reading the buffers we are about to overwrite
    __builtin_amdgcn_s_barrier();
    if (t + 1 < NT) stageB(t + 1, (t + 1) & 1);
    if (t + 2 < NT) { stageA(t + 2, bufAn); bufAn = (bufAn == 2) ? 0 : bufAn + 1; }
    // counted wait: tile t's loads (issued 1-2 tiles ago) landed; newer stay in flight
    if (t < NT - 2)       asm volatile("s_waitcnt vmcnt(12)" ::: "memory");
    else if (t == NT - 2) asm volatile("s_waitcnt vmcnt(8)"  ::: "memory");
    else                  asm volatile("s_waitcnt vmcnt(0)"  ::: "memory");
    __builtin_amdgcn_sched_barrier(0);
    // barrier_B: all waves' vmcnt satisfied -> tile t fully staged
    __builtin_amdgcn_s_barrier();
    __builtin_amdgcn_sched_barrier(0);

    const u16* Ab = &As[bufA][0];
    const u16* Bb = &Bs[t & 1][0];
    bufA = (bufA == 2) ? 0 : bufA + 1;

    bf16x8 af[4][2], bfr[4][2];
#pragma unroll
    for (int mt = 0; mt < 4; mt++)
#pragma unroll
      for (int ks = 0; ks < 2; ks++)
        af[mt][ks] = *(const bf16x8*)(&Ab[(wr * 64 + mt * 16 + l15) * 64 + (((ks * 4 + quad) ^ x7) * 8)]);
#pragma unroll
    for (int nt = 0; nt < 4; nt++)
#pragma unroll
      for (int ks = 0; ks < 2; ks++)
        bfr[nt][ks] = *(const bf16x8*)(&Bb[(wc * 64 + nt * 16 + l15) * 64 + (((ks * 4 + quad) ^ x7) * 8)]);
#pragma unroll
    for (int ks = 0; ks < 2; ks++)
#pragma unroll
      for (int mt = 0; mt < 4; mt++)
#pragma unroll
        for (int nt = 0; nt < 4; nt++)
          acc[mt][nt] = __builtin_amdgcn_mfma_f32_16x16x32_bf16(af[mt][ks], bfr[nt][ks], acc[mt][nt], 0, 0, 0);
  }

  if constexpr (MODE == 0) {
    u16* out = (u16*)Cout;
    if (tn < 1024) {
      // Q half -> [B,H,T,Dh]
#pragma unroll
      for (int mt = 0; mt < 4; mt++)
#pragma unroll
        for (int nt = 0; nt < 4; nt++)
#pragma unroll
          for (int r = 0; r < 4; r++) {
            int gm = tm + wr * 64 + mt * 16 + quad * 4 + r;
            int gn = tn + wc * 64 + nt * 16 + l15;
            int b = gm >> 11, tt = gm & 2047;
            int h = gn >> 6, d = gn & 63;
            out[((size_t)((b * 16 + h) * 2048 + tt) << 6) + d] = f2b(acc[mt][nt][r]);
          }
    } else {
      // V half -> Vt [B,H,Dh,T] (fused transpose)
#pragma unroll
      for (int mt = 0; mt < 4; mt++)
#pragma unroll
        for (int nt = 0; nt < 4; nt++) {
          int gm0 = tm + wr * 64 + mt * 16 + quad * 4;
          int gn  = tn - 1024 + wc * 64 + nt * 16 + l15;
          int b = gm0 >> 11, t0 = gm0 & 2047;
          int h = gn >> 6, d = gn & 63;
          alignas(8) u16 tmp[4];
#pragma unroll
          for (int r = 0; r < 4; r++) tmp[r] = f2b(acc[mt][nt][r]);
          *(ushort4*)(out + 8388608 + (((size_t)(b * 16 + h) * 64 + d) << 11) + t0)
              = *(const ushort4*)tmp;
        }
    }
  } else {
    float* out = (float*)Cout;
#pragma unroll
    for (int mt = 0; mt < 4; mt++)
#pragma unroll
      for (int nt = 0; nt < 4; nt++)
#pragma unroll
        for (int r = 0; r < 4; r++) {
          int gm = tm + wr * 64 + mt * 16 + quad * 4 + r;
          int gn = tn + wc * 64 + nt * 16 + l15;
          out[(size_t)gm * 1024 + gn] = acc[mt][nt][r];
        }
  }
}

// ---------------- causal flash attention, K==Q (reference bug), bf16 MFMA ----------------
// v7: R6 structure (1024 blocks, LPT, 4 blk/CU, one barrier/k-tile) + 3-op pair-pack
// for P (round-half-up +0x8000 then v_perm_b32 high-half merge) replacing 32x scalar
// f2b (~190 insts/tile -> ~48). VALU was 43.8% busy at 356 insts/tile -- the pack
// was over half of it.
__global__ __launch_bounds__(256, 4) void attn_kernel(
    const u16* __restrict__ Q, const u16* __restrict__ Vt, u16* __restrict__ AO)
{
  __shared__ __align__(16) u16 Ks[2][4096];     // [buf][key 64][dh 64] swizzled, 16KB
  __shared__ __align__(16) u16 Vs[2][4096];     // [buf][d 64][key 64] swizzled, 16KB

  const int tid  = threadIdx.x;
  const int wave = tid >> 6, lane = tid & 63;
  const int quad = lane >> 4, l15 = lane & 15;
  const int x7   = l15 & 7;
  // A-row m holds key f(m) = swap bits 2<->3: makes register pairs (r,r+1) =
  // consecutive keys AND quad halves line up so permlane32_swap alone builds PV frags
  const int krow = (l15 & 3) | ((l15 & 4) << 1) | ((l15 & 8) >> 1);
  const int kx7  = krow & 7;
  const int bid  = blockIdx.x;
  // bits 0-5: bh, XCD-packed (bid%8 -> XCD; each XCD owns 8 bh = 4MB Q+Vt = its L2)
  const int bh = (bid & 7) * 8 + ((bid >> 3) & 7);
  const int m  = bid >> 6;                       // 0..15
  // balanced-LPT q-tile map: CU's resident set {m, m+4, m+8, m+12} sums to 68 tiles
  const int i  = (m & 4) ? ((m & 8) ? m - 12 : m + 4) : 15 - m;
  const int b = bh >> 4, h = bh & 15;
  const u16* Qbh = Q  + (size_t)bh * (T_ * DH_);
  const u16* Vbh = Vt + (size_t)bh * (DH_ * T_);
  const int q0w = i * 128 + wave * 32;     // wave's first q-row
  const int kbd = (q0w + 31) >> 6;         // wave's diagonal k-tile
  const int nkb = 2 * i + 2;               // block-level k-tiles (64 keys each)

  const bf16x8 ones = { 0x3F80, 0x3F80, 0x3F80, 0x3F80, 0x3F80, 0x3F80, 0x3F80, 0x3F80 };

  auto stage = [&](int kb, int bufi) {
    const int k0 = kb * 64;
#pragma unroll
    for (int it = 0; it < 2; it++) {
      int ch  = it * 256 + tid;
      int row = ch >> 3;
      int cc  = (ch & 7) ^ (row & 7);
      GLDS16(Qbh + (size_t)(k0 + row) * DH_ + cc * 8, &Ks[bufi][(it * 256 + wave * 64) * 8]);
      GLDS16(Vbh + (size_t)row * T_ + k0 + cc * 8,    &Vs[bufi][(it * 256 + wave * 64) * 8]);
    }
  };

  // issue first stage before the (independent) qf loads
  stage(0, 0);

  // Q fragments: once per block, direct global (used as the MFMA B operand)
  bf16x8 qf[2][2];
#pragma unroll
  for (int mt = 0; mt < 2; mt++)
#pragma unroll
    for (int ks = 0; ks < 2; ks++)
      qf[mt][ks] = *(const bf16x8*)(Qbh + (size_t)(q0w + mt * 16 + l15) * DH_ + ks * 32 + quad * 8);

  f32x4 o[2][4] = {};
  f32x4 lsumv[2] = {};

  auto tilecomp = [&](int kb, int bufi, auto DIAGC) {
    constexpr bool DIAG = decltype(DIAGC)::value;
    const int k0 = kb * 64;
    const u16* KsB = Ks[bufi];
    const u16* VsB = Vs[bufi];

    // S^T = K Q^T : C col = l15 = query, C row = quad*4+r = permuted key f(row)
    f32x4 s[2][4] = {};
#pragma unroll
    for (int ks = 0; ks < 2; ks++)
#pragma unroll
      for (int nt = 0; nt < 4; nt++) {
        bf16x8 kf = *(const bf16x8*)(&KsB[(nt * 16 + krow) * 64 + (((ks * 4 + quad) ^ kx7) * 8)]);
#pragma unroll
        for (int mt = 0; mt < 2; mt++)
          s[mt][nt] = __builtin_amdgcn_mfma_f32_16x16x32_bf16(kf, qf[mt][ks], s[mt][nt], 0, 0, 0);
      }

    // unnormalized softmax: p = exp2(s) (scale pre-folded into W_q; common factor
    // cancels in O = sum(PV)/sum(P)). 3-op pair-pack to bf16x2 words.
    // lane (quad,l15): regs r hold keys (quad&1)*8 + (quad>>1)*4 + r (within nt*16)
    unsigned c[2][4][2];
#pragma unroll
    for (int mt = 0; mt < 2; mt++)
#pragma unroll
      for (int nt = 0; nt < 4; nt++) {
        float pv[4];
#pragma unroll
        for (int r = 0; r < 4; r++) {
          float pe = __builtin_amdgcn_exp2f(s[mt][nt][r]);
          if constexpr (DIAG) {
            int qg = q0w + mt * 16 + l15;
            int kg = k0 + nt * 16 + (quad & 1) * 8 + (quad >> 1) * 4 + r;
            pe = (kg <= qg) ? pe : 0.0f;
          }
          pv[r] = pe;
        }
        c[mt][nt][0] = pkbf16(pv[0], pv[1]);
        c[mt][nt][1] = pkbf16(pv[2], pv[3]);
      }

    // O += P V ; PV A-fragment built via permlane32_swap
#pragma unroll
    for (int ks2 = 0; ks2 < 2; ks2++) {
      bf16x8 pf[2];
#pragma unroll
      for (int mt = 0; mt < 2; mt++) {
        u32x2 w02 = __builtin_amdgcn_permlane32_swap(c[mt][2 * ks2][0], c[mt][2 * ks2 + 1][0], false, false);
        u32x2 w13 = __builtin_amdgcn_permlane32_swap(c[mt][2 * ks2][1], c[mt][2 * ks2 + 1][1], false, false);
        union { unsigned u[4]; bf16x8 v; } pk;
        pk.u[0] = w02[0]; pk.u[1] = w13[0]; pk.u[2] = w02[1]; pk.u[3] = w13[1];
        pf[mt] = pk.v;
        // row-sums via ones-MFMA (rides the MFMA pipe; rows = query quad*4+r)
        lsumv[mt] = __builtin_amdgcn_mfma_f32_16x16x32_bf16(pf[mt], ones, lsumv[mt], 0, 0, 0);
      }
#pragma unroll
      for (int dt = 0; dt < 4; dt++) {
        bf16x8 vf = *(const bf16x8*)(&VsB[(dt * 16 + l15) * 64 + (((ks2 * 4 + quad) ^ x7) * 8)]);
#pragma unroll
        for (int mt = 0; mt < 2; mt++)
          o[mt][dt] = __builtin_amdgcn_mfma_f32_16x16x32_bf16(pf[mt], vf, o[mt][dt], 0, 0, 0);
      }
    }
  };

  for (int kb = 0; kb < nkb; kb++) {
    __syncthreads();                        // drains stage(kb); all waves past compute(kb-1)
    if (kb + 1 < nkb) stage(kb + 1, (kb + 1) & 1);
    const int bufi = kb & 1;
    if (kb < kbd)        tilecomp(kb, bufi, std::false_type{});
    else if (kb == kbd)  tilecomp(kb, bufi, std::true_type{});
  }

  // epilogue: lsumv already holds full row sums (identical across the 16-lane col group)
#pragma unroll
  for (int mt = 0; mt < 2; mt++)
#pragma unroll
    for (int r = 0; r < 4; r++) {
      float rl = 1.0f / lsumv[mt][r];
      int t = q0w + mt * 16 + quad * 4 + r;
#pragma unroll
      for (int dt = 0; dt < 4; dt++)
        AO[((size_t)(b * T_ + t)) * C_ + h * DH_ + dt * 16 + l15] = f2b(o[mt][dt][r] * rl);
    }
}

extern "C" void kernel_launch(void* const* d_in, const int* in_sizes, int n_in,
                              void* d_out, int out_size, void* d_ws, size_t ws_size,
                              hipStream_t stream) {
  (void)in_sizes; (void)n_in; (void)out_size; (void)ws_size;
  const float* x  = (const float*)d_in[0];
  const float* Wq = (const float*)d_in[1];
  // d_in[2] = W_k unused (reference bug: K uses W_q)
  const float* Wv = (const float*)d_in[3];
  const float* Wo = (const float*)d_in[4];

  // workspace (u16 elems); AO reuses Xb slot (dead after gemm1)
  u16* Xb  = (u16*)d_ws;            // 8388608 : x bf16; later AO [B,T,C]
  u16* AOw = Xb;
  u16* Wqb = Xb  + 8388608;         // 1048576
  u16* Wvb = Wqb + 1048576;         // 1048576 (adjacent -> fused N=2048 GEMM)
  u16* Wob = Wvb + 1048576;         // 1048576
  u16* Qw  = Wob + 1048576;         // 8388608 : Q [B,H,T,Dh] (pre-scaled by sqrt(C1))
  u16* Vtw = Qw  + 8388608;         // 8388608 : Vt [B,H,Dh,T] (gemm1 writes directly)
  // total 54,525,952 bytes

  cast_all_kernel<<<11264, 256, 0, stream>>>(x, Wq, Wv, Wo, Xb, Wqb, Wvb, Wob);

  // fused Q+V projection; V half written pre-transposed (Vt base = Qw + 8388608)
  gemm128_kernel<0><<<dim3(64, 16), 256, 0, stream>>>(Xb, Wqb, (void*)Qw);

  attn_kernel<<<1024, 256, 0, stream>>>(Qw, Vtw, AOw);

  // output projection: fp32 out
  gemm128_kernel<1><<<dim3(64, 8), 256, 0, stream>>>(AOw, Wob, (void*)d_out);
}

// Round 10
// 196.955 us; speedup vs baseline: 1.0024x; 1.0024x over previous
//
#include <hip/hip_runtime.h>
#include <hip/hip_bf16.h>
#include <type_traits>

typedef unsigned short u16;
typedef __attribute__((ext_vector_type(8))) short bf16x8;
typedef __attribute__((ext_vector_type(4))) float f32x4;
typedef __attribute__((ext_vector_type(2))) unsigned int u32x2;

#define B_  4
#define T_  2048
#define C_  1024
#define H_  16
#define DH_ 64
#define M_  (B_*T_)   // 8192

// async global->LDS, 16B per lane; LDS dest = wave-uniform base + lane*16
#define GLDS16(g, l) __builtin_amdgcn_global_load_lds( \
    (const __attribute__((address_space(1))) void*)(g), \
    (__attribute__((address_space(3))) void*)(l), 16, 0, 0)

__device__ __forceinline__ u16 f2b(float f) {
  union { __hip_bfloat16 h; u16 u; } cv;
  cv.h = __float2bfloat16(f);
  return cv.u;
}

// ---------------- all fp32 -> bf16 casts in one launch ----------------
// W_q is pre-scaled by sqrt(log2(e)/8): both Q and K flow through W_q (reference bug),
// so QK^T arrives pre-multiplied by log2(e)/sqrt(64) and attn's softmax is a bare exp2.
__global__ void cast_all_kernel(const float* __restrict__ x,  const float* __restrict__ w0,
                                const float* __restrict__ w1, const float* __restrict__ w2,
                                u16* __restrict__ xo, u16* __restrict__ o0,
                                u16* __restrict__ o1, u16* __restrict__ o2) {
  int bid = blockIdx.x;
  const float* src; u16* dst; int blk;
  float sc = 1.0f;
  if (bid < 8192) { src = x; dst = xo; blk = bid; }
  else {
    int k = bid - 8192, w = k >> 10;
    src = (w == 0) ? w0 : (w == 1) ? w1 : w2;
    dst = (w == 0) ? o0 : (w == 1) ? o1 : o2;
    blk = k & 1023;
    if (w == 0) sc = 0.42466088f;     // sqrt(log2(e)/8)
  }
  int i = (blk * 256 + threadIdx.x) * 4;
  float4 v = *(const float4*)(src + i);
  unsigned lo = (unsigned)f2b(v.x * sc) | ((unsigned)f2b(v.y * sc) << 16);
  unsigned hi = (unsigned)f2b(v.z * sc) | ((unsigned)f2b(v.w * sc) << 16);
  uint2 p; p.x = lo; p.y = hi;
  *(uint2*)(dst + i) = p;
}

// ---------------- pipelined GEMM: 128x128 tile, 4 waves, counted vmcnt, 2 blk/CU ----
// C[m,n] = sum_k A[m,k]*B[n,k], BK=64, K=1024 (16 k-tiles).
// A: 3 bufs (48KB), B: 2 bufs (32KB) -> 80KB LDS, EXACTLY 2 blocks/CU (160KB):
// co-resident blocks cover each other's vmcnt/barrier stalls. Counted-vmcnt ledger
// (4-load stages): prologue B0,A0,A1 = 12 in flight; per tile t issue B(t+1),A(t+2)
// then vmcnt(12); tails vmcnt(8), vmcnt(0).
// MODE 0: bf16 scatter epilogue (Q half -> [B,H,T,Dh], V half -> Vt [B,H,Dh,T]).
// MODE 1: fp32 linear out [M,N].
template<int MODE>
__global__ __launch_bounds__(256, 2) void gemm128_kernel(
    const u16* __restrict__ A, const u16* __restrict__ Bm, void* __restrict__ Cout)
{
  constexpr int K = 1024;
  constexpr int NT = K / 64;                 // 16 k-tiles
  __shared__ __align__(16) u16 As[3][128 * 64];   // 48KB
  __shared__ __align__(16) u16 Bs[2][128 * 64];   // 32KB

  const int tid  = threadIdx.x;
  const int wave = tid >> 6, lane = tid & 63;     // wave 0..3
  const int quad = lane >> 4, l15 = lane & 15;
  const int x7   = l15 & 7;
  const int wr = wave >> 1, wc = wave & 1;        // 2x2 wave grid, 64x64 tiles
  // XCD-chunked swizzle (bijective: gridDim.x==64 -> 8 x-panels per XCD).
  const int ord = blockIdx.y * gridDim.x + blockIdx.x;  // dispatch order (x fastest)
  const int xcd = ord & 7;
  const int loc = ord >> 3;
  const int xl  = loc & 7;
  const int yy  = loc >> 3;
  const int tm = (xcd * 8 + xl) * 128, tn = yy * 128;

  f32x4 acc[4][4] = {};

  auto stageA = [&](int t, int bi) {
    const int k0 = t * 64;
#pragma unroll
    for (int it = 0; it < 4; it++) {
      int ch  = it * 256 + tid;       // 0..1023 chunks (128 rows x 8)
      int row = ch >> 3;
      int cc  = (ch & 7) ^ (row & 7);
      GLDS16(A + (size_t)(tm + row) * K + k0 + cc * 8, &As[bi][(it * 256 + wave * 64) * 8]);
    }
  };
  auto stageB = [&](int t, int bi) {
    const int k0 = t * 64;
#pragma unroll
    for (int it = 0; it < 4; it++) {
      int ch  = it * 256 + tid;
      int row = ch >> 3;
      int cc  = (ch & 7) ^ (row & 7);
      GLDS16(Bm + (size_t)(tn + row) * K + k0 + cc * 8, &Bs[bi][(it * 256 + wave * 64) * 8]);
    }
  };

  // prologue: B(0) [4], A(0) [4], A(1) [4]  -> 12 vmem insts in flight per wave
  stageB(0, 0);
  stageA(0, 0);
  stageA(1, 1);

  int bufA = 0, bufAn = 2;     // t%3 and (t+2)%3 trackers
  for (int t = 0; t < NT; t++) {
    // barrier_A: every wave is done reading the buffers we are about to overwrite
    __builtin_amdgcn_s_barrier();
    if (t + 1 < NT) stageB(t + 1, (t + 1) & 1);
    if (t + 2 < NT) { stageA(t + 2, bufAn); bufAn = (bufAn == 2) ? 0 : bufAn + 1; }
    // counted wait: tile t's loads (issued 1-2 tiles ago) landed; newer stay in flight
    if (t < NT - 2)       asm volatile("s_waitcnt vmcnt(12)" ::: "memory");
    else if (t == NT - 2) asm volatile("s_waitcnt vmcnt(8)"  ::: "memory");
    else                  asm volatile("s_waitcnt vmcnt(0)"  ::: "memory");
    __builtin_amdgcn_sched_barrier(0);
    // barrier_B: all waves' vmcnt satisfied -> tile t fully staged
    __builtin_amdgcn_s_barrier();
    __builtin_amdgcn_sched_barrier(0);

    const u16* Ab = &As[bufA][0];
    const u16* Bb = &Bs[t & 1][0];
    bufA = (bufA == 2) ? 0 : bufA + 1;

    bf16x8 af[4][2], bfr[4][2];
#pragma unroll
    for (int mt = 0; mt < 4; mt++)
#pragma unroll
      for (int ks = 0; ks < 2; ks++)
        af[mt][ks] = *(const bf16x8*)(&Ab[(wr * 64 + mt * 16 + l15) * 64 + (((ks * 4 + quad) ^ x7) * 8)]);
#pragma unroll
    for (int nt = 0; nt < 4; nt++)
#pragma unroll
      for (int ks = 0; ks < 2; ks++)
        bfr[nt][ks] = *(const bf16x8*)(&Bb[(wc * 64 + nt * 16 + l15) * 64 + (((ks * 4 + quad) ^ x7) * 8)]);
#pragma unroll
    for (int ks = 0; ks < 2; ks++)
#pragma unroll
      for (int mt = 0; mt < 4; mt++)
#pragma unroll
        for (int nt = 0; nt < 4; nt++)
          acc[mt][nt] = __builtin_amdgcn_mfma_f32_16x16x32_bf16(af[mt][ks], bfr[nt][ks], acc[mt][nt], 0, 0, 0);
  }

  if constexpr (MODE == 0) {
    u16* out = (u16*)Cout;
    if (tn < 1024) {
      // Q half -> [B,H,T,Dh]
#pragma unroll
      for (int mt = 0; mt < 4; mt++)
#pragma unroll
        for (int nt = 0; nt < 4; nt++)
#pragma unroll
          for (int r = 0; r < 4; r++) {
            int gm = tm + wr * 64 + mt * 16 + quad * 4 + r;
            int gn = tn + wc * 64 + nt * 16 + l15;
            int b = gm >> 11, tt = gm & 2047;
            int h = gn >> 6, d = gn & 63;
            out[((size_t)((b * 16 + h) * 2048 + tt) << 6) + d] = f2b(acc[mt][nt][r]);
          }
    } else {
      // V half -> Vt [B,H,Dh,T] (fused transpose)
#pragma unroll
      for (int mt = 0; mt < 4; mt++)
#pragma unroll
        for (int nt = 0; nt < 4; nt++) {
          int gm0 = tm + wr * 64 + mt * 16 + quad * 4;
          int gn  = tn - 1024 + wc * 64 + nt * 16 + l15;
          int b = gm0 >> 11, t0 = gm0 & 2047;
          int h = gn >> 6, d = gn & 63;
          alignas(8) u16 tmp[4];
#pragma unroll
          for (int r = 0; r < 4; r++) tmp[r] = f2b(acc[mt][nt][r]);
          *(ushort4*)(out + 8388608 + (((size_t)(b * 16 + h) * 64 + d) << 11) + t0)
              = *(const ushort4*)tmp;
        }
    }
  } else {
    float* out = (float*)Cout;
#pragma unroll
    for (int mt = 0; mt < 4; mt++)
#pragma unroll
      for (int nt = 0; nt < 4; nt++)
#pragma unroll
        for (int r = 0; r < 4; r++) {
          int gm = tm + wr * 64 + mt * 16 + quad * 4 + r;
          int gn = tn + wc * 64 + nt * 16 + l15;
          out[(size_t)gm * 1024 + gn] = acc[mt][nt][r];
        }
  }
}

// ---------------- causal flash attention, K==Q (reference bug), bf16 MFMA ----------------
// v8: R8 structure + pack restored to f2b (R9 counters PROVED the compiler already
// fuses f2b pairs to v_cvt_pk_bf16_f32 -- hand 3-op pack ADDED instructions:
// VALUBusy 43.4 -> 49.1, dur +1.8us; m240's lesson reproduced). New, isolated:
// s_setprio(1) around both MFMA clusters (T5/m191: +4-7% for independent-block attn;
// never cleanly tested on this structure -- R4/R5 were confounded).
__global__ __launch_bounds__(256, 4) void attn_kernel(
    const u16* __restrict__ Q, const u16* __restrict__ Vt, u16* __restrict__ AO)
{
  __shared__ __align__(16) u16 Ks[2][4096];     // [buf][key 64][dh 64] swizzled, 16KB
  __shared__ __align__(16) u16 Vs[2][4096];     // [buf][d 64][key 64] swizzled, 16KB

  const int tid  = threadIdx.x;
  const int wave = tid >> 6, lane = tid & 63;
  const int quad = lane >> 4, l15 = lane & 15;
  const int x7   = l15 & 7;
  // A-row m holds key f(m) = swap bits 2<->3: makes register pairs (r,r+1) =
  // consecutive keys AND quad halves line up so permlane32_swap alone builds PV frags
  const int krow = (l15 & 3) | ((l15 & 4) << 1) | ((l15 & 8) >> 1);
  const int kx7  = krow & 7;
  const int bid  = blockIdx.x;
  // bits 0-5: bh, XCD-packed (bid%8 -> XCD; each XCD owns 8 bh = 4MB Q+Vt = its L2)
  const int bh = (bid & 7) * 8 + ((bid >> 3) & 7);
  const int m  = bid >> 6;                       // 0..15
  // balanced-LPT q-tile map: CU's resident set {m, m+4, m+8, m+12} sums to 68 tiles
  const int i  = (m & 4) ? ((m & 8) ? m - 12 : m + 4) : 15 - m;
  const int b = bh >> 4, h = bh & 15;
  const u16* Qbh = Q  + (size_t)bh * (T_ * DH_);
  const u16* Vbh = Vt + (size_t)bh * (DH_ * T_);
  const int q0w = i * 128 + wave * 32;     // wave's first q-row
  const int kbd = (q0w + 31) >> 6;         // wave's diagonal k-tile
  const int nkb = 2 * i + 2;               // block-level k-tiles (64 keys each)

  const bf16x8 ones = { 0x3F80, 0x3F80, 0x3F80, 0x3F80, 0x3F80, 0x3F80, 0x3F80, 0x3F80 };

  auto stage = [&](int kb, int bufi) {
    const int k0 = kb * 64;
#pragma unroll
    for (int it = 0; it < 2; it++) {
      int ch  = it * 256 + tid;
      int row = ch >> 3;
      int cc  = (ch & 7) ^ (row & 7);
      GLDS16(Qbh + (size_t)(k0 + row) * DH_ + cc * 8, &Ks[bufi][(it * 256 + wave * 64) * 8]);
      GLDS16(Vbh + (size_t)row * T_ + k0 + cc * 8,    &Vs[bufi][(it * 256 + wave * 64) * 8]);
    }
  };

  // issue first stage before the (independent) qf loads
  stage(0, 0);

  // Q fragments: once per block, direct global (used as the MFMA B operand)
  bf16x8 qf[2][2];
#pragma unroll
  for (int mt = 0; mt < 2; mt++)
#pragma unroll
    for (int ks = 0; ks < 2; ks++)
      qf[mt][ks] = *(const bf16x8*)(Qbh + (size_t)(q0w + mt * 16 + l15) * DH_ + ks * 32 + quad * 8);

  f32x4 o[2][4] = {};
  f32x4 lsumv[2] = {};

  auto tilecomp = [&](int kb, int bufi, auto DIAGC) {
    constexpr bool DIAG = decltype(DIAGC)::value;
    const int k0 = kb * 64;
    const u16* KsB = Ks[bufi];
    const u16* VsB = Vs[bufi];

    // S^T = K Q^T : C col = l15 = query, C row = quad*4+r = permuted key f(row)
    f32x4 s[2][4] = {};
    __builtin_amdgcn_s_setprio(1);
#pragma unroll
    for (int ks = 0; ks < 2; ks++)
#pragma unroll
      for (int nt = 0; nt < 4; nt++) {
        bf16x8 kf = *(const bf16x8*)(&KsB[(nt * 16 + krow) * 64 + (((ks * 4 + quad) ^ kx7) * 8)]);
#pragma unroll
        for (int mt = 0; mt < 2; mt++)
          s[mt][nt] = __builtin_amdgcn_mfma_f32_16x16x32_bf16(kf, qf[mt][ks], s[mt][nt], 0, 0, 0);
      }
    __builtin_amdgcn_s_setprio(0);

    // unnormalized softmax: p = exp2(s) (scale pre-folded into W_q; common factor
    // cancels in O = sum(PV)/sum(P)). Pack key pairs (f2b shift-OR; compiler fuses
    // adjacent pairs to v_cvt_pk_bf16_f32 -- do NOT hand-write the pack, R9/m240).
    // lane (quad,l15): regs r hold keys (quad&1)*8 + (quad>>1)*4 + r (within nt*16)
    unsigned c[2][4][2];
#pragma unroll
    for (int mt = 0; mt < 2; mt++)
#pragma unroll
      for (int nt = 0; nt < 4; nt++) {
        u16 pb[4];
#pragma unroll
        for (int r = 0; r < 4; r++) {
          float pe = __builtin_amdgcn_exp2f(s[mt][nt][r]);
          if constexpr (DIAG) {
            int qg = q0w + mt * 16 + l15;
            int kg = k0 + nt * 16 + (quad & 1) * 8 + (quad >> 1) * 4 + r;
            pe = (kg <= qg) ? pe : 0.0f;
          }
          pb[r] = f2b(pe);
        }
        c[mt][nt][0] = (unsigned)pb[0] | ((unsigned)pb[1] << 16);
        c[mt][nt][1] = (unsigned)pb[2] | ((unsigned)pb[3] << 16);
      }

    // O += P V ; PV A-fragment built via permlane32_swap
#pragma unroll
    for (int ks2 = 0; ks2 < 2; ks2++) {
      bf16x8 pf[2];
#pragma unroll
      for (int mt = 0; mt < 2; mt++) {
        u32x2 w02 = __builtin_amdgcn_permlane32_swap(c[mt][2 * ks2][0], c[mt][2 * ks2 + 1][0], false, false);
        u32x2 w13 = __builtin_amdgcn_permlane32_swap(c[mt][2 * ks2][1], c[mt][2 * ks2 + 1][1], false, false);
        union { unsigned u[4]; bf16x8 v; } pk;
        pk.u[0] = w02[0]; pk.u[1] = w13[0]; pk.u[2] = w02[1]; pk.u[3] = w13[1];
        pf[mt] = pk.v;
      }
      __builtin_amdgcn_s_setprio(1);
#pragma unroll
      for (int mt = 0; mt < 2; mt++)
        lsumv[mt] = __builtin_amdgcn_mfma_f32_16x16x32_bf16(pf[mt], ones, lsumv[mt], 0, 0, 0);
#pragma unroll
      for (int dt = 0; dt < 4; dt++) {
        bf16x8 vf = *(const bf16x8*)(&VsB[(dt * 16 + l15) * 64 + (((ks2 * 4 + quad) ^ x7) * 8)]);
#pragma unroll
        for (int mt = 0; mt < 2; mt++)
          o[mt][dt] = __builtin_amdgcn_mfma_f32_16x16x32_bf16(pf[mt], vf, o[mt][dt], 0, 0, 0);
      }
      __builtin_amdgcn_s_setprio(0);
    }
  };

  for (int kb = 0; kb < nkb; kb++) {
    __syncthreads();                        // drains stage(kb); all waves past compute(kb-1)
    if (kb + 1 < nkb) stage(kb + 1, (kb + 1) & 1);
    const int bufi = kb & 1;
    if (kb < kbd)        tilecomp(kb, bufi, std::false_type{});
    else if (kb == kbd)  tilecomp(kb, bufi, std::true_type{});
  }

  // epilogue: lsumv already holds full row sums (identical across the 16-lane col group)
#pragma unroll
  for (int mt = 0; mt < 2; mt++)
#pragma unroll
    for (int r = 0; r < 4; r++) {
      float rl = 1.0f / lsumv[mt][r];
      int t = q0w + mt * 16 + quad * 4 + r;
#pragma unroll
      for (int dt = 0; dt < 4; dt++)
        AO[((size_t)(b * T_ + t)) * C_ + h * DH_ + dt * 16 + l15] = f2b(o[mt][dt][r] * rl);
    }
}

extern "C" void kernel_launch(void* const* d_in, const int* in_sizes, int n_in,
                              void* d_out, int out_size, void* d_ws, size_t ws_size,
                              hipStream_t stream) {
  (void)in_sizes; (void)n_in; (void)out_size; (void)ws_size;
  const float* x  = (const float*)d_in[0];
  const float* Wq = (const float*)d_in[1];
  // d_in[2] = W_k unused (reference bug: K uses W_q)
  const float* Wv = (const float*)d_in[3];
  const float* Wo = (const float*)d_in[4];

  // workspace (u16 elems); AO reuses Xb slot (dead after gemm1)
  u16* Xb  = (u16*)d_ws;            // 8388608 : x bf16; later AO [B,T,C]
  u16* AOw = Xb;
  u16* Wqb = Xb  + 8388608;         // 1048576
  u16* Wvb = Wqb + 1048576;         // 1048576 (adjacent -> fused N=2048 GEMM)
  u16* Wob = Wvb + 1048576;         // 1048576
  u16* Qw  = Wob + 1048576;         // 8388608 : Q [B,H,T,Dh] (pre-scaled by sqrt(C1))
  u16* Vtw = Qw  + 8388608;         // 8388608 : Vt [B,H,Dh,T] (gemm1 writes directly)
  // total 54,525,952 bytes

  cast_all_kernel<<<11264, 256, 0, stream>>>(x, Wq, Wv, Wo, Xb, Wqb, Wvb, Wob);

  // fused Q+V projection; V half written pre-transposed (Vt base = Qw + 8388608)
  gemm128_kernel<0><<<dim3(64, 16), 256, 0, stream>>>(Xb, Wqb, (void*)Qw);

  attn_kernel<<<1024, 256, 0, stream>>>(Qw, Vtw, AOw);

  // output projection: fp32 out
  gemm128_kernel<1><<<dim3(64, 8), 256, 0, stream>>>(AOw, Wob, (void*)d_out);
}

// Round 11
// 195.249 us; speedup vs baseline: 1.0112x; 1.0087x over previous
//
#include <hip/hip_runtime.h>
#include <hip/hip_bf16.h>
#include <type_traits>

typedef unsigned short u16;
typedef __attribute__((ext_vector_type(8))) short bf16x8;
typedef __attribute__((ext_vector_type(4))) float f32x4;
typedef __attribute__((ext_vector_type(2))) unsigned int u32x2;

#define B_  4
#define T_  2048
#define C_  1024
#define H_  16
#define DH_ 64
#define M_  (B_*T_)   // 8192

// async global->LDS, 16B per lane; LDS dest = wave-uniform base + lane*16
#define GLDS16(g, l) __builtin_amdgcn_global_load_lds( \
    (const __attribute__((address_space(1))) void*)(g), \
    (__attribute__((address_space(3))) void*)(l), 16, 0, 0)

__device__ __forceinline__ u16 f2b(float f) {
  union { __hip_bfloat16 h; u16 u; } cv;
  cv.h = __float2bfloat16(f);
  return cv.u;
}

// ---------------- all fp32 -> bf16 casts in one launch ----------------
// W_q is pre-scaled by sqrt(log2(e)/8): both Q and K flow through W_q (reference bug),
// so QK^T arrives pre-multiplied by log2(e)/sqrt(64) and attn's softmax is a bare exp2.
__global__ void cast_all_kernel(const float* __restrict__ x,  const float* __restrict__ w0,
                                const float* __restrict__ w1, const float* __restrict__ w2,
                                u16* __restrict__ xo, u16* __restrict__ o0,
                                u16* __restrict__ o1, u16* __restrict__ o2) {
  int bid = blockIdx.x;
  const float* src; u16* dst; int blk;
  float sc = 1.0f;
  if (bid < 8192) { src = x; dst = xo; blk = bid; }
  else {
    int k = bid - 8192, w = k >> 10;
    src = (w == 0) ? w0 : (w == 1) ? w1 : w2;
    dst = (w == 0) ? o0 : (w == 1) ? o1 : o2;
    blk = k & 1023;
    if (w == 0) sc = 0.42466088f;     // sqrt(log2(e)/8)
  }
  int i = (blk * 256 + threadIdx.x) * 4;
  float4 v = *(const float4*)(src + i);
  unsigned lo = (unsigned)f2b(v.x * sc) | ((unsigned)f2b(v.y * sc) << 16);
  unsigned hi = (unsigned)f2b(v.z * sc) | ((unsigned)f2b(v.w * sc) << 16);
  uint2 p; p.x = lo; p.y = hi;
  *(uint2*)(dst + i) = p;
}

// ---------------- pipelined GEMM: 128x128 tile, 4 waves, counted vmcnt, 2 blk/CU ----
// C[m,n] = sum_k A[m,k]*B[n,k], BK=64, K=1024 (16 k-tiles).
// A: 3 bufs (48KB), B: 2 bufs (32KB) -> 80KB LDS, EXACTLY 2 blocks/CU (160KB):
// co-resident blocks cover each other's vmcnt/barrier stalls. Counted-vmcnt ledger
// (4-load stages): prologue B0,A0,A1 = 12 in flight; per tile t issue B(t+1),A(t+2)
// then vmcnt(12); tails vmcnt(8), vmcnt(0).
// MODE 0: bf16 scatter epilogue (Q half -> [B,H,T,Dh], V half -> Vt [B,H,Dh,T]).
// MODE 1: fp32 linear out [M,N].
template<int MODE>
__global__ __launch_bounds__(256, 2) void gemm128_kernel(
    const u16* __restrict__ A, const u16* __restrict__ Bm, void* __restrict__ Cout)
{
  constexpr int K = 1024;
  constexpr int NT = K / 64;                 // 16 k-tiles
  __shared__ __align__(16) u16 As[3][128 * 64];   // 48KB
  __shared__ __align__(16) u16 Bs[2][128 * 64];   // 32KB

  const int tid  = threadIdx.x;
  const int wave = tid >> 6, lane = tid & 63;     // wave 0..3
  const int quad = lane >> 4, l15 = lane & 15;
  const int x7   = l15 & 7;
  const int wr = wave >> 1, wc = wave & 1;        // 2x2 wave grid, 64x64 tiles
  // XCD-chunked swizzle (bijective: gridDim.x==64 -> 8 x-panels per XCD).
  const int ord = blockIdx.y * gridDim.x + blockIdx.x;  // dispatch order (x fastest)
  const int xcd = ord & 7;
  const int loc = ord >> 3;
  const int xl  = loc & 7;
  const int yy  = loc >> 3;
  const int tm = (xcd * 8 + xl) * 128, tn = yy * 128;

  f32x4 acc[4][4] = {};

  auto stageA = [&](int t, int bi) {
    const int k0 = t * 64;
#pragma unroll
    for (int it = 0; it < 4; it++) {
      int ch  = it * 256 + tid;       // 0..1023 chunks (128 rows x 8)
      int row = ch >> 3;
      int cc  = (ch & 7) ^ (row & 7);
      GLDS16(A + (size_t)(tm + row) * K + k0 + cc * 8, &As[bi][(it * 256 + wave * 64) * 8]);
    }
  };
  auto stageB = [&](int t, int bi) {
    const int k0 = t * 64;
#pragma unroll
    for (int it = 0; it < 4; it++) {
      int ch  = it * 256 + tid;
      int row = ch >> 3;
      int cc  = (ch & 7) ^ (row & 7);
      GLDS16(Bm + (size_t)(tn + row) * K + k0 + cc * 8, &Bs[bi][(it * 256 + wave * 64) * 8]);
    }
  };

  // prologue: B(0) [4], A(0) [4], A(1) [4]  -> 12 vmem insts in flight per wave
  stageB(0, 0);
  stageA(0, 0);
  stageA(1, 1);

  int bufA = 0, bufAn = 2;     // t%3 and (t+2)%3 trackers
  for (int t = 0; t < NT; t++) {
    // barrier_A: every wave is done reading the buffers we are about to overwrite
    __builtin_amdgcn_s_barrier();
    if (t + 1 < NT) stageB(t + 1, (t + 1) & 1);
    if (t + 2 < NT) { stageA(t + 2, bufAn); bufAn = (bufAn == 2) ? 0 : bufAn + 1; }
    // counted wait: tile t's loads (issued 1-2 tiles ago) landed; newer stay in flight
    if (t < NT - 2)       asm volatile("s_waitcnt vmcnt(12)" ::: "memory");
    else if (t == NT - 2) asm volatile("s_waitcnt vmcnt(8)"  ::: "memory");
    else                  asm volatile("s_waitcnt vmcnt(0)"  ::: "memory");
    __builtin_amdgcn_sched_barrier(0);
    // barrier_B: all waves' vmcnt satisfied -> tile t fully staged
    __builtin_amdgcn_s_barrier();
    __builtin_amdgcn_sched_barrier(0);

    const u16* Ab = &As[bufA][0];
    const u16* Bb = &Bs[t & 1][0];
    bufA = (bufA == 2) ? 0 : bufA + 1;

    bf16x8 af[4][2], bfr[4][2];
#pragma unroll
    for (int mt = 0; mt < 4; mt++)
#pragma unroll
      for (int ks = 0; ks < 2; ks++)
        af[mt][ks] = *(const bf16x8*)(&Ab[(wr * 64 + mt * 16 + l15) * 64 + (((ks * 4 + quad) ^ x7) * 8)]);
#pragma unroll
    for (int nt = 0; nt < 4; nt++)
#pragma unroll
      for (int ks = 0; ks < 2; ks++)
        bfr[nt][ks] = *(const bf16x8*)(&Bb[(wc * 64 + nt * 16 + l15) * 64 + (((ks * 4 + quad) ^ x7) * 8)]);
#pragma unroll
    for (int ks = 0; ks < 2; ks++)
#pragma unroll
      for (int mt = 0; mt < 4; mt++)
#pragma unroll
        for (int nt = 0; nt < 4; nt++)
          acc[mt][nt] = __builtin_amdgcn_mfma_f32_16x16x32_bf16(af[mt][ks], bfr[nt][ks], acc[mt][nt], 0, 0, 0);
  }

  if constexpr (MODE == 0) {
    u16* out = (u16*)Cout;
    if (tn < 1024) {
      // Q half -> [B,H,T,Dh]
#pragma unroll
      for (int mt = 0; mt < 4; mt++)
#pragma unroll
        for (int nt = 0; nt < 4; nt++)
#pragma unroll
          for (int r = 0; r < 4; r++) {
            int gm = tm + wr * 64 + mt * 16 + quad * 4 + r;
            int gn = tn + wc * 64 + nt * 16 + l15;
            int b = gm >> 11, tt = gm & 2047;
            int h = gn >> 6, d = gn & 63;
            out[((size_t)((b * 16 + h) * 2048 + tt) << 6) + d] = f2b(acc[mt][nt][r]);
          }
    } else {
      // V half -> Vt [B,H,Dh,T] (fused transpose)
#pragma unroll
      for (int mt = 0; mt < 4; mt++)
#pragma unroll
        for (int nt = 0; nt < 4; nt++) {
          int gm0 = tm + wr * 64 + mt * 16 + quad * 4;
          int gn  = tn - 1024 + wc * 64 + nt * 16 + l15;
          int b = gm0 >> 11, t0 = gm0 & 2047;
          int h = gn >> 6, d = gn & 63;
          alignas(8) u16 tmp[4];
#pragma unroll
          for (int r = 0; r < 4; r++) tmp[r] = f2b(acc[mt][nt][r]);
          *(ushort4*)(out + 8388608 + (((size_t)(b * 16 + h) * 64 + d) << 11) + t0)
              = *(const ushort4*)tmp;
        }
    }
  } else {
    float* out = (float*)Cout;
#pragma unroll
    for (int mt = 0; mt < 4; mt++)
#pragma unroll
      for (int nt = 0; nt < 4; nt++)
#pragma unroll
        for (int r = 0; r < 4; r++) {
          int gm = tm + wr * 64 + mt * 16 + quad * 4 + r;
          int gn = tn + wc * 64 + nt * 16 + l15;
          out[(size_t)gm * 1024 + gn] = acc[mt][nt][r];
        }
  }
}

// ---------------- causal flash attention, K==Q (reference bug), bf16 MFMA ----------------
// v9: R8 structure with setprio REMOVED (R10 A/B: 45.3 -> 47.6, T5 needs phase-split
// role diversity which this single-phase loop lacks). New: counted-vmcnt double-barrier
// k-loop (the gemm's proven pattern): s_barrier / issue stage(kb+1) / vmcnt(4) drains
// exactly stage(kb) / s_barrier / compute -- stage(kb+1)'s loads stay in flight across
// the barrier, gaining a full tile of latency slack vs __syncthreads' vmcnt(0) drain.
// Ledger: prologue = stage0(4) + qf(4) = 8 outstanding; iter kb issues 4 -> vmcnt(4)
// leaves stage(kb+1) flying; buffer overwrite only after barrier proves compute(kb-1)
// done with it; last iter vmcnt(0).
__global__ __launch_bounds__(256, 4) void attn_kernel(
    const u16* __restrict__ Q, const u16* __restrict__ Vt, u16* __restrict__ AO)
{
  __shared__ __align__(16) u16 Ks[2][4096];     // [buf][key 64][dh 64] swizzled, 16KB
  __shared__ __align__(16) u16 Vs[2][4096];     // [buf][d 64][key 64] swizzled, 16KB

  const int tid  = threadIdx.x;
  const int wave = tid >> 6, lane = tid & 63;
  const int quad = lane >> 4, l15 = lane & 15;
  const int x7   = l15 & 7;
  // A-row m holds key f(m) = swap bits 2<->3: makes register pairs (r,r+1) =
  // consecutive keys AND quad halves line up so permlane32_swap alone builds PV frags
  const int krow = (l15 & 3) | ((l15 & 4) << 1) | ((l15 & 8) >> 1);
  const int kx7  = krow & 7;
  const int bid  = blockIdx.x;
  // bits 0-5: bh, XCD-packed (bid%8 -> XCD; each XCD owns 8 bh = 4MB Q+Vt = its L2)
  const int bh = (bid & 7) * 8 + ((bid >> 3) & 7);
  const int m  = bid >> 6;                       // 0..15
  // balanced-LPT q-tile map: CU's resident set {m, m+4, m+8, m+12} sums to 68 tiles
  const int i  = (m & 4) ? ((m & 8) ? m - 12 : m + 4) : 15 - m;
  const int b = bh >> 4, h = bh & 15;
  const u16* Qbh = Q  + (size_t)bh * (T_ * DH_);
  const u16* Vbh = Vt + (size_t)bh * (DH_ * T_);
  const int q0w = i * 128 + wave * 32;     // wave's first q-row
  const int kbd = (q0w + 31) >> 6;         // wave's diagonal k-tile
  const int nkb = 2 * i + 2;               // block-level k-tiles (64 keys each)

  const bf16x8 ones = { 0x3F80, 0x3F80, 0x3F80, 0x3F80, 0x3F80, 0x3F80, 0x3F80, 0x3F80 };

  auto stage = [&](int kb, int bufi) {
    const int k0 = kb * 64;
#pragma unroll
    for (int it = 0; it < 2; it++) {
      int ch  = it * 256 + tid;
      int row = ch >> 3;
      int cc  = (ch & 7) ^ (row & 7);
      GLDS16(Qbh + (size_t)(k0 + row) * DH_ + cc * 8, &Ks[bufi][(it * 256 + wave * 64) * 8]);
      GLDS16(Vbh + (size_t)row * T_ + k0 + cc * 8,    &Vs[bufi][(it * 256 + wave * 64) * 8]);
    }
  };

  // issue first stage before the (independent) qf loads
  stage(0, 0);

  // Q fragments: once per block, direct global (used as the MFMA B operand)
  bf16x8 qf[2][2];
#pragma unroll
  for (int mt = 0; mt < 2; mt++)
#pragma unroll
    for (int ks = 0; ks < 2; ks++)
      qf[mt][ks] = *(const bf16x8*)(Qbh + (size_t)(q0w + mt * 16 + l15) * DH_ + ks * 32 + quad * 8);

  f32x4 o[2][4] = {};
  f32x4 lsumv[2] = {};

  auto tilecomp = [&](int kb, int bufi, auto DIAGC) {
    constexpr bool DIAG = decltype(DIAGC)::value;
    const int k0 = kb * 64;
    const u16* KsB = Ks[bufi];
    const u16* VsB = Vs[bufi];

    // S^T = K Q^T : C col = l15 = query, C row = quad*4+r = permuted key f(row)
    f32x4 s[2][4] = {};
#pragma unroll
    for (int ks = 0; ks < 2; ks++)
#pragma unroll
      for (int nt = 0; nt < 4; nt++) {
        bf16x8 kf = *(const bf16x8*)(&KsB[(nt * 16 + krow) * 64 + (((ks * 4 + quad) ^ kx7) * 8)]);
#pragma unroll
        for (int mt = 0; mt < 2; mt++)
          s[mt][nt] = __builtin_amdgcn_mfma_f32_16x16x32_bf16(kf, qf[mt][ks], s[mt][nt], 0, 0, 0);
      }

    // unnormalized softmax: p = exp2(s) (scale pre-folded into W_q; common factor
    // cancels in O = sum(PV)/sum(P)). Pack key pairs (f2b shift-OR; compiler fuses
    // adjacent pairs to v_cvt_pk_bf16_f32 -- do NOT hand-write the pack, R9/m240).
    // lane (quad,l15): regs r hold keys (quad&1)*8 + (quad>>1)*4 + r (within nt*16)
    unsigned c[2][4][2];
#pragma unroll
    for (int mt = 0; mt < 2; mt++)
#pragma unroll
      for (int nt = 0; nt < 4; nt++) {
        u16 pb[4];
#pragma unroll
        for (int r = 0; r < 4; r++) {
          float pe = __builtin_amdgcn_exp2f(s[mt][nt][r]);
          if constexpr (DIAG) {
            int qg = q0w + mt * 16 + l15;
            int kg = k0 + nt * 16 + (quad & 1) * 8 + (quad >> 1) * 4 + r;
            pe = (kg <= qg) ? pe : 0.0f;
          }
          pb[r] = f2b(pe);
        }
        c[mt][nt][0] = (unsigned)pb[0] | ((unsigned)pb[1] << 16);
        c[mt][nt][1] = (unsigned)pb[2] | ((unsigned)pb[3] << 16);
      }

    // O += P V ; PV A-fragment built via permlane32_swap
#pragma unroll
    for (int ks2 = 0; ks2 < 2; ks2++) {
      bf16x8 pf[2];
#pragma unroll
      for (int mt = 0; mt < 2; mt++) {
        u32x2 w02 = __builtin_amdgcn_permlane32_swap(c[mt][2 * ks2][0], c[mt][2 * ks2 + 1][0], false, false);
        u32x2 w13 = __builtin_amdgcn_permlane32_swap(c[mt][2 * ks2][1], c[mt][2 * ks2 + 1][1], false, false);
        union { unsigned u[4]; bf16x8 v; } pk;
        pk.u[0] = w02[0]; pk.u[1] = w13[0]; pk.u[2] = w02[1]; pk.u[3] = w13[1];
        pf[mt] = pk.v;
        // row-sums via ones-MFMA (rides the MFMA pipe; rows = query quad*4+r)
        lsumv[mt] = __builtin_amdgcn_mfma_f32_16x16x32_bf16(pf[mt], ones, lsumv[mt], 0, 0, 0);
      }
#pragma unroll
      for (int dt = 0; dt < 4; dt++) {
        bf16x8 vf = *(const bf16x8*)(&VsB[(dt * 16 + l15) * 64 + (((ks2 * 4 + quad) ^ x7) * 8)]);
#pragma unroll
        for (int mt = 0; mt < 2; mt++)
          o[mt][dt] = __builtin_amdgcn_mfma_f32_16x16x32_bf16(pf[mt], vf, o[mt][dt], 0, 0, 0);
      }
    }
  };

  for (int kb = 0; kb < nkb; kb++) {
    // barrier_A: all waves past compute(kb-1) -> buf[(kb+1)&1] safe to overwrite
    __builtin_amdgcn_s_barrier();
    if (kb + 1 < nkb) {
      stage(kb + 1, (kb + 1) & 1);
      asm volatile("s_waitcnt vmcnt(4)" ::: "memory");   // drains stage(kb) (+qf at kb=0)
    } else {
      asm volatile("s_waitcnt vmcnt(0)" ::: "memory");   // last tile: drain everything
    }
    __builtin_amdgcn_sched_barrier(0);
    // barrier_B: all waves see stage(kb) complete
    __builtin_amdgcn_s_barrier();
    __builtin_amdgcn_sched_barrier(0);

    const int bufi = kb & 1;
    if (kb < kbd)        tilecomp(kb, bufi, std::false_type{});
    else if (kb == kbd)  tilecomp(kb, bufi, std::true_type{});
  }

  // epilogue: lsumv already holds full row sums (identical across the 16-lane col group)
#pragma unroll
  for (int mt = 0; mt < 2; mt++)
#pragma unroll
    for (int r = 0; r < 4; r++) {
      float rl = 1.0f / lsumv[mt][r];
      int t = q0w + mt * 16 + quad * 4 + r;
#pragma unroll
      for (int dt = 0; dt < 4; dt++)
        AO[((size_t)(b * T_ + t)) * C_ + h * DH_ + dt * 16 + l15] = f2b(o[mt][dt][r] * rl);
    }
}

extern "C" void kernel_launch(void* const* d_in, const int* in_sizes, int n_in,
                              void* d_out, int out_size, void* d_ws, size_t ws_size,
                              hipStream_t stream) {
  (void)in_sizes; (void)n_in; (void)out_size; (void)ws_size;
  const float* x  = (const float*)d_in[0];
  const float* Wq = (const float*)d_in[1];
  // d_in[2] = W_k unused (reference bug: K uses W_q)
  const float* Wv = (const float*)d_in[3];
  const float* Wo = (const float*)d_in[4];

  // workspace (u16 elems); AO reuses Xb slot (dead after gemm1)
  u16* Xb  = (u16*)d_ws;            // 8388608 : x bf16; later AO [B,T,C]
  u16* AOw = Xb;
  u16* Wqb = Xb  + 8388608;         // 1048576
  u16* Wvb = Wqb + 1048576;         // 1048576 (adjacent -> fused N=2048 GEMM)
  u16* Wob = Wvb + 1048576;         // 1048576
  u16* Qw  = Wob + 1048576;         // 8388608 : Q [B,H,T,Dh] (pre-scaled by sqrt(C1))
  u16* Vtw = Qw  + 8388608;         // 8388608 : Vt [B,H,Dh,T] (gemm1 writes directly)
  // total 54,525,952 bytes

  cast_all_kernel<<<11264, 256, 0, stream>>>(x, Wq, Wv, Wo, Xb, Wqb, Wvb, Wob);

  // fused Q+V projection; V half written pre-transposed (Vt base = Qw + 8388608)
  gemm128_kernel<0><<<dim3(64, 16), 256, 0, stream>>>(Xb, Wqb, (void*)Qw);

  attn_kernel<<<1024, 256, 0, stream>>>(Qw, Vtw, AOw);

  // output projection: fp32 out
  gemm128_kernel<1><<<dim3(64, 8), 256, 0, stream>>>(AOw, Wob, (void*)d_out);
}

// Round 12
// 190.453 us; speedup vs baseline: 1.0367x; 1.0252x over previous
//
#include <hip/hip_runtime.h>
#include <hip/hip_bf16.h>
#include <type_traits>

typedef unsigned short u16;
typedef __attribute__((ext_vector_type(8))) short bf16x8;
typedef __attribute__((ext_vector_type(4))) float f32x4;
typedef __attribute__((ext_vector_type(2))) unsigned int u32x2;

#define B_  4
#define T_  2048
#define C_  1024
#define H_  16
#define DH_ 64
#define M_  (B_*T_)   // 8192

// async global->LDS, 16B per lane; LDS dest = wave-uniform base + lane*16
#define GLDS16(g, l) __builtin_amdgcn_global_load_lds( \
    (const __attribute__((address_space(1))) void*)(g), \
    (__attribute__((address_space(3))) void*)(l), 16, 0, 0)

__device__ __forceinline__ u16 f2b(float f) {
  union { __hip_bfloat16 h; u16 u; } cv;
  cv.h = __float2bfloat16(f);
  return cv.u;
}

// ---------------- all fp32 -> bf16 casts in one launch ----------------
// W_q is pre-scaled by sqrt(log2(e)/8): both Q and K flow through W_q (reference bug),
// so QK^T arrives pre-multiplied by log2(e)/sqrt(64) and attn's softmax is a bare exp2.
__global__ void cast_all_kernel(const float* __restrict__ x,  const float* __restrict__ w0,
                                const float* __restrict__ w1, const float* __restrict__ w2,
                                u16* __restrict__ xo, u16* __restrict__ o0,
                                u16* __restrict__ o1, u16* __restrict__ o2) {
  int bid = blockIdx.x;
  const float* src; u16* dst; int blk;
  float sc = 1.0f;
  if (bid < 8192) { src = x; dst = xo; blk = bid; }
  else {
    int k = bid - 8192, w = k >> 10;
    src = (w == 0) ? w0 : (w == 1) ? w1 : w2;
    dst = (w == 0) ? o0 : (w == 1) ? o1 : o2;
    blk = k & 1023;
    if (w == 0) sc = 0.42466088f;     // sqrt(log2(e)/8)
  }
  int i = (blk * 256 + threadIdx.x) * 4;
  float4 v = *(const float4*)(src + i);
  unsigned lo = (unsigned)f2b(v.x * sc) | ((unsigned)f2b(v.y * sc) << 16);
  unsigned hi = (unsigned)f2b(v.z * sc) | ((unsigned)f2b(v.w * sc) << 16);
  uint2 p; p.x = lo; p.y = hi;
  *(uint2*)(dst + i) = p;
}

// ---------------- pipelined GEMM: 128x128 tile, 4 waves, counted vmcnt, 2 blk/CU ----
// C[m,n] = sum_k A[m,k]*B[n,k], BK=64, K=1024 (16 k-tiles).
// A: 3 bufs (48KB), B: 2 bufs (32KB) -> 80KB LDS, 2 blocks/CU (160KB).
// Counted-vmcnt ledger (4-load stages): prologue B0,A0,A1 = 12 in flight; per tile t
// issue B(t+1),A(t+2) then vmcnt(12); tails vmcnt(8), vmcnt(0).
// MODE 0: bf16 scatter epilogue (Q half -> [B,H,T,Dh], V half -> Vt [B,H,Dh,T]).
// MODE 1: fp32 linear out [M,N].
template<int MODE>
__global__ __launch_bounds__(256, 2) void gemm128_kernel(
    const u16* __restrict__ A, const u16* __restrict__ Bm, void* __restrict__ Cout)
{
  constexpr int K = 1024;
  constexpr int NT = K / 64;                 // 16 k-tiles
  __shared__ __align__(16) u16 As[3][128 * 64];   // 48KB
  __shared__ __align__(16) u16 Bs[2][128 * 64];   // 32KB

  const int tid  = threadIdx.x;
  const int wave = tid >> 6, lane = tid & 63;     // wave 0..3
  const int quad = lane >> 4, l15 = lane & 15;
  const int x7   = l15 & 7;
  const int wr = wave >> 1, wc = wave & 1;        // 2x2 wave grid, 64x64 tiles
  // XCD-chunked swizzle (bijective: gridDim.x==64 -> 8 x-panels per XCD).
  const int ord = blockIdx.y * gridDim.x + blockIdx.x;  // dispatch order (x fastest)
  const int xcd = ord & 7;
  const int loc = ord >> 3;
  const int xl  = loc & 7;
  const int yy  = loc >> 3;
  const int tm = (xcd * 8 + xl) * 128, tn = yy * 128;

  f32x4 acc[4][4] = {};

  auto stageA = [&](int t, int bi) {
    const int k0 = t * 64;
#pragma unroll
    for (int it = 0; it < 4; it++) {
      int ch  = it * 256 + tid;       // 0..1023 chunks (128 rows x 8)
      int row = ch >> 3;
      int cc  = (ch & 7) ^ (row & 7);
      GLDS16(A + (size_t)(tm + row) * K + k0 + cc * 8, &As[bi][(it * 256 + wave * 64) * 8]);
    }
  };
  auto stageB = [&](int t, int bi) {
    const int k0 = t * 64;
#pragma unroll
    for (int it = 0; it < 4; it++) {
      int ch  = it * 256 + tid;
      int row = ch >> 3;
      int cc  = (ch & 7) ^ (row & 7);
      GLDS16(Bm + (size_t)(tn + row) * K + k0 + cc * 8, &Bs[bi][(it * 256 + wave * 64) * 8]);
    }
  };

  // prologue: B(0) [4], A(0) [4], A(1) [4]  -> 12 vmem insts in flight per wave
  stageB(0, 0);
  stageA(0, 0);
  stageA(1, 1);

  int bufA = 0, bufAn = 2;     // t%3 and (t+2)%3 trackers
  for (int t = 0; t < NT; t++) {
    // barrier_A: every wave is done reading the buffers we are about to overwrite
    __builtin_amdgcn_s_barrier();
    if (t + 1 < NT) stageB(t + 1, (t + 1) & 1);
    if (t + 2 < NT) { stageA(t + 2, bufAn); bufAn = (bufAn == 2) ? 0 : bufAn + 1; }
    // counted wait: tile t's loads (issued 1-2 tiles ago) landed; newer stay in flight
    if (t < NT - 2)       asm volatile("s_waitcnt vmcnt(12)" ::: "memory");
    else if (t == NT - 2) asm volatile("s_waitcnt vmcnt(8)"  ::: "memory");
    else                  asm volatile("s_waitcnt vmcnt(0)"  ::: "memory");
    __builtin_amdgcn_sched_barrier(0);
    // barrier_B: all waves' vmcnt satisfied -> tile t fully staged
    __builtin_amdgcn_s_barrier();
    __builtin_amdgcn_sched_barrier(0);

    const u16* Ab = &As[bufA][0];
    const u16* Bb = &Bs[t & 1][0];
    bufA = (bufA == 2) ? 0 : bufA + 1;

    bf16x8 af[4][2], bfr[4][2];
#pragma unroll
    for (int mt = 0; mt < 4; mt++)
#pragma unroll
      for (int ks = 0; ks < 2; ks++)
        af[mt][ks] = *(const bf16x8*)(&Ab[(wr * 64 + mt * 16 + l15) * 64 + (((ks * 4 + quad) ^ x7) * 8)]);
#pragma unroll
    for (int nt = 0; nt < 4; nt++)
#pragma unroll
      for (int ks = 0; ks < 2; ks++)
        bfr[nt][ks] = *(const bf16x8*)(&Bb[(wc * 64 + nt * 16 + l15) * 64 + (((ks * 4 + quad) ^ x7) * 8)]);
#pragma unroll
    for (int ks = 0; ks < 2; ks++)
#pragma unroll
      for (int mt = 0; mt < 4; mt++)
#pragma unroll
        for (int nt = 0; nt < 4; nt++)
          acc[mt][nt] = __builtin_amdgcn_mfma_f32_16x16x32_bf16(af[mt][ks], bfr[nt][ks], acc[mt][nt], 0, 0, 0);
  }

  if constexpr (MODE == 0) {
    u16* out = (u16*)Cout;
    if (tn < 1024) {
      // Q half -> [B,H,T,Dh]
#pragma unroll
      for (int mt = 0; mt < 4; mt++)
#pragma unroll
        for (int nt = 0; nt < 4; nt++)
#pragma unroll
          for (int r = 0; r < 4; r++) {
            int gm = tm + wr * 64 + mt * 16 + quad * 4 + r;
            int gn = tn + wc * 64 + nt * 16 + l15;
            int b = gm >> 11, tt = gm & 2047;
            int h = gn >> 6, d = gn & 63;
            out[((size_t)((b * 16 + h) * 2048 + tt) << 6) + d] = f2b(acc[mt][nt][r]);
          }
    } else {
      // V half -> Vt [B,H,Dh,T] (fused transpose)
#pragma unroll
      for (int mt = 0; mt < 4; mt++)
#pragma unroll
        for (int nt = 0; nt < 4; nt++) {
          int gm0 = tm + wr * 64 + mt * 16 + quad * 4;
          int gn  = tn - 1024 + wc * 64 + nt * 16 + l15;
          int b = gm0 >> 11, t0 = gm0 & 2047;
          int h = gn >> 6, d = gn & 63;
          alignas(8) u16 tmp[4];
#pragma unroll
          for (int r = 0; r < 4; r++) tmp[r] = f2b(acc[mt][nt][r]);
          *(ushort4*)(out + 8388608 + (((size_t)(b * 16 + h) * 64 + d) << 11) + t0)
              = *(const ushort4*)tmp;
        }
    }
  } else {
    float* out = (float*)Cout;
#pragma unroll
    for (int mt = 0; mt < 4; mt++)
#pragma unroll
      for (int nt = 0; nt < 4; nt++)
#pragma unroll
        for (int r = 0; r < 4; r++) {
          int gm = tm + wr * 64 + mt * 16 + quad * 4 + r;
          int gn = tn + wc * 64 + nt * 16 + l15;
          out[(size_t)gm * 1024 + gn] = acc[mt][nt][r];
        }
  }
}

// ---------------- causal flash attention, K==Q (reference bug), bf16 MFMA ----------------
// v10 == R8 exact (best measured: 45.3us). History of A/B results on this structure:
//  - setprio around MFMA clusters: -2.3us regression (R10; T5 needs phase-split)
//  - hand-written cvt_pk/perm pack:  -1.8us regression (R9; compiler already fuses f2b
//    pairs to v_cvt_pk_bf16_f32 -- m240)
//  - counted-vmcnt double-barrier:   neutral/-0.6 (R11; stage latency already hidden
//    by 4 blk/CU cross-block overlap, m114)
//  - two-phase balanced blocks:      -9us regression (R4; blocks/CU > balance)
// Structure: 1024 blocks, XCD-packed bh, LPT q-tile map, 4 blk/CU, double-buffered
// K/V, one __syncthreads per k-tile; swapped QK^T (S^T = K*Q^T) + in-register P
// (f2b pack + permlane32_swap); unnormalized softmax p = exp2(s) (scale folded
// into W_q at cast); lsum via ones-MFMA.
__global__ __launch_bounds__(256, 4) void attn_kernel(
    const u16* __restrict__ Q, const u16* __restrict__ Vt, u16* __restrict__ AO)
{
  __shared__ __align__(16) u16 Ks[2][4096];     // [buf][key 64][dh 64] swizzled, 16KB
  __shared__ __align__(16) u16 Vs[2][4096];     // [buf][d 64][key 64] swizzled, 16KB

  const int tid  = threadIdx.x;
  const int wave = tid >> 6, lane = tid & 63;
  const int quad = lane >> 4, l15 = lane & 15;
  const int x7   = l15 & 7;
  // A-row m holds key f(m) = swap bits 2<->3: makes register pairs (r,r+1) =
  // consecutive keys AND quad halves line up so permlane32_swap alone builds PV frags
  const int krow = (l15 & 3) | ((l15 & 4) << 1) | ((l15 & 8) >> 1);
  const int kx7  = krow & 7;
  const int bid  = blockIdx.x;
  // bits 0-5: bh, XCD-packed (bid%8 -> XCD; each XCD owns 8 bh = 4MB Q+Vt = its L2)
  const int bh = (bid & 7) * 8 + ((bid >> 3) & 7);
  const int m  = bid >> 6;                       // 0..15
  // balanced-LPT q-tile map: CU's resident set {m, m+4, m+8, m+12} sums to 68 tiles
  const int i  = (m & 4) ? ((m & 8) ? m - 12 : m + 4) : 15 - m;
  const int b = bh >> 4, h = bh & 15;
  const u16* Qbh = Q  + (size_t)bh * (T_ * DH_);
  const u16* Vbh = Vt + (size_t)bh * (DH_ * T_);
  const int q0w = i * 128 + wave * 32;     // wave's first q-row
  const int kbd = (q0w + 31) >> 6;         // wave's diagonal k-tile
  const int nkb = 2 * i + 2;               // block-level k-tiles (64 keys each)

  const bf16x8 ones = { 0x3F80, 0x3F80, 0x3F80, 0x3F80, 0x3F80, 0x3F80, 0x3F80, 0x3F80 };

  auto stage = [&](int kb, int bufi) {
    const int k0 = kb * 64;
#pragma unroll
    for (int it = 0; it < 2; it++) {
      int ch  = it * 256 + tid;
      int row = ch >> 3;
      int cc  = (ch & 7) ^ (row & 7);
      GLDS16(Qbh + (size_t)(k0 + row) * DH_ + cc * 8, &Ks[bufi][(it * 256 + wave * 64) * 8]);
      GLDS16(Vbh + (size_t)row * T_ + k0 + cc * 8,    &Vs[bufi][(it * 256 + wave * 64) * 8]);
    }
  };

  // issue first stage before the (independent) qf loads
  stage(0, 0);

  // Q fragments: once per block, direct global (used as the MFMA B operand)
  bf16x8 qf[2][2];
#pragma unroll
  for (int mt = 0; mt < 2; mt++)
#pragma unroll
    for (int ks = 0; ks < 2; ks++)
      qf[mt][ks] = *(const bf16x8*)(Qbh + (size_t)(q0w + mt * 16 + l15) * DH_ + ks * 32 + quad * 8);

  f32x4 o[2][4] = {};
  f32x4 lsumv[2] = {};

  auto tilecomp = [&](int kb, int bufi, auto DIAGC) {
    constexpr bool DIAG = decltype(DIAGC)::value;
    const int k0 = kb * 64;
    const u16* KsB = Ks[bufi];
    const u16* VsB = Vs[bufi];

    // S^T = K Q^T : C col = l15 = query, C row = quad*4+r = permuted key f(row)
    f32x4 s[2][4] = {};
#pragma unroll
    for (int ks = 0; ks < 2; ks++)
#pragma unroll
      for (int nt = 0; nt < 4; nt++) {
        bf16x8 kf = *(const bf16x8*)(&KsB[(nt * 16 + krow) * 64 + (((ks * 4 + quad) ^ kx7) * 8)]);
#pragma unroll
        for (int mt = 0; mt < 2; mt++)
          s[mt][nt] = __builtin_amdgcn_mfma_f32_16x16x32_bf16(kf, qf[mt][ks], s[mt][nt], 0, 0, 0);
      }

    // unnormalized softmax: p = exp2(s) (scale pre-folded into W_q; common factor
    // cancels in O = sum(PV)/sum(P)). Pack key pairs (f2b shift-OR; compiler fuses
    // adjacent pairs to v_cvt_pk_bf16_f32 -- do NOT hand-write the pack, R9/m240).
    // lane (quad,l15): regs r hold keys (quad&1)*8 + (quad>>1)*4 + r (within nt*16)
    unsigned c[2][4][2];
#pragma unroll
    for (int mt = 0; mt < 2; mt++)
#pragma unroll
      for (int nt = 0; nt < 4; nt++) {
        u16 pb[4];
#pragma unroll
        for (int r = 0; r < 4; r++) {
          float pe = __builtin_amdgcn_exp2f(s[mt][nt][r]);
          if constexpr (DIAG) {
            int qg = q0w + mt * 16 + l15;
            int kg = k0 + nt * 16 + (quad & 1) * 8 + (quad >> 1) * 4 + r;
            pe = (kg <= qg) ? pe : 0.0f;
          }
          pb[r] = f2b(pe);
        }
        c[mt][nt][0] = (unsigned)pb[0] | ((unsigned)pb[1] << 16);
        c[mt][nt][1] = (unsigned)pb[2] | ((unsigned)pb[3] << 16);
      }

    // O += P V ; PV A-fragment built via permlane32_swap
#pragma unroll
    for (int ks2 = 0; ks2 < 2; ks2++) {
      bf16x8 pf[2];
#pragma unroll
      for (int mt = 0; mt < 2; mt++) {
        u32x2 w02 = __builtin_amdgcn_permlane32_swap(c[mt][2 * ks2][0], c[mt][2 * ks2 + 1][0], false, false);
        u32x2 w13 = __builtin_amdgcn_permlane32_swap(c[mt][2 * ks2][1], c[mt][2 * ks2 + 1][1], false, false);
        union { unsigned u[4]; bf16x8 v; } pk;
        pk.u[0] = w02[0]; pk.u[1] = w13[0]; pk.u[2] = w02[1]; pk.u[3] = w13[1];
        pf[mt] = pk.v;
        // row-sums via ones-MFMA (rides the MFMA pipe; rows = query quad*4+r)
        lsumv[mt] = __builtin_amdgcn_mfma_f32_16x16x32_bf16(pf[mt], ones, lsumv[mt], 0, 0, 0);
      }
#pragma unroll
      for (int dt = 0; dt < 4; dt++) {
        bf16x8 vf = *(const bf16x8*)(&VsB[(dt * 16 + l15) * 64 + (((ks2 * 4 + quad) ^ x7) * 8)]);
#pragma unroll
        for (int mt = 0; mt < 2; mt++)
          o[mt][dt] = __builtin_amdgcn_mfma_f32_16x16x32_bf16(pf[mt], vf, o[mt][dt], 0, 0, 0);
      }
    }
  };

  for (int kb = 0; kb < nkb; kb++) {
    __syncthreads();                        // drains stage(kb); all waves past compute(kb-1)
    if (kb + 1 < nkb) stage(kb + 1, (kb + 1) & 1);
    const int bufi = kb & 1;
    if (kb < kbd)        tilecomp(kb, bufi, std::false_type{});
    else if (kb == kbd)  tilecomp(kb, bufi, std::true_type{});
  }

  // epilogue: lsumv already holds full row sums (identical across the 16-lane col group)
#pragma unroll
  for (int mt = 0; mt < 2; mt++)
#pragma unroll
    for (int r = 0; r < 4; r++) {
      float rl = 1.0f / lsumv[mt][r];
      int t = q0w + mt * 16 + quad * 4 + r;
#pragma unroll
      for (int dt = 0; dt < 4; dt++)
        AO[((size_t)(b * T_ + t)) * C_ + h * DH_ + dt * 16 + l15] = f2b(o[mt][dt][r] * rl);
    }
}

extern "C" void kernel_launch(void* const* d_in, const int* in_sizes, int n_in,
                              void* d_out, int out_size, void* d_ws, size_t ws_size,
                              hipStream_t stream) {
  (void)in_sizes; (void)n_in; (void)out_size; (void)ws_size;
  const float* x  = (const float*)d_in[0];
  const float* Wq = (const float*)d_in[1];
  // d_in[2] = W_k unused (reference bug: K uses W_q)
  const float* Wv = (const float*)d_in[3];
  const float* Wo = (const float*)d_in[4];

  // workspace (u16 elems); AO reuses Xb slot (dead after gemm1)
  u16* Xb  = (u16*)d_ws;            // 8388608 : x bf16; later AO [B,T,C]
  u16* AOw = Xb;
  u16* Wqb = Xb  + 8388608;         // 1048576
  u16* Wvb = Wqb + 1048576;         // 1048576 (adjacent -> fused N=2048 GEMM)
  u16* Wob = Wvb + 1048576;         // 1048576
  u16* Qw  = Wob + 1048576;         // 8388608 : Q [B,H,T,Dh] (pre-scaled by sqrt(C1))
  u16* Vtw = Qw  + 8388608;         // 8388608 : Vt [B,H,Dh,T] (gemm1 writes directly)
  // total 54,525,952 bytes

  cast_all_kernel<<<11264, 256, 0, stream>>>(x, Wq, Wv, Wo, Xb, Wqb, Wvb, Wob);

  // fused Q+V projection; V half written pre-transposed (Vt base = Qw + 8388608)
  gemm128_kernel<0><<<dim3(64, 16), 256, 0, stream>>>(Xb, Wqb, (void*)Qw);

  attn_kernel<<<1024, 256, 0, stream>>>(Qw, Vtw, AOw);

  // output projection: fp32 out
  gemm128_kernel<1><<<dim3(64, 8), 256, 0, stream>>>(AOw, Wob, (void*)d_out);
}